// Round 1
// baseline (54.662 us; speedup 1.0000x reference)
//
#include <hip/hip_runtime.h>

// Analytic reduction of the FQCNN circuit:
//   - H on wires 0-3 -> uniform over 16 configs b.
//   - The 4 RYs all target wire 4 and commute; accumulated angle per config:
//       theta_b = p0 + p1*(b0&b2) + p2*(b1&b3) + p3*(b0&b1)
//   - H on wire 5 and the controlled-U3s on wire 6 are unitary on wires 5/6
//     per fixed config of wires 0-5 -> wire-4 marginal unchanged. U3_w unused.
//   - expval(Z_4) = (1/16) sum_b cos(theta_b)
//       = (1/16) Re[ e^{ip0} (8 + 2e^{ip1} + 2e^{ip2}
//                             + e^{ip3}(1+e^{ip1})(1+e^{ip2})) ]
// Memory-bound elementwise map: 16 B read + 8 B write per thread (2 patches).

__device__ __forceinline__ float ev4(float p0, float p1, float p2, float p3) {
    float s0, c0, s1, c1, s2, c2, s3, c3;
    __sincosf(p0, &s0, &c0);
    __sincosf(p1, &s1, &c1);
    __sincosf(p2, &s2, &c2);
    __sincosf(p3, &s3, &c3);
    // (1+e^{ip1}) * (1+e^{ip2})
    float ar = 1.0f + c1, ai = s1;
    float br = 1.0f + c2, bi = s2;
    float mr = ar * br - ai * bi;
    float mi = ar * bi + ai * br;
    // * e^{ip3}
    float tr = c3 * mr - s3 * mi;
    float ti = c3 * mi + s3 * mr;
    float Sr = 8.0f + 2.0f * c1 + 2.0f * c2 + tr;
    float Si = 2.0f * s1 + 2.0f * s2 + ti;
    return (c0 * Sr - s0 * Si) * 0.0625f;
}

__global__ __launch_bounds__(256) void fqcnn_kernel(const float* __restrict__ x,
                                                    float* __restrict__ out,
                                                    int n_pairs) {
    int t = blockIdx.x * blockDim.x + threadIdx.x;
    if (t >= n_pairs) return;
    // Each thread: 2 horizontally-adjacent 2x2 patches.
    int kp  = t & 31;   // which float4 within the input row (32 per row)
    int rp  = t >> 5;   // img * 64 + j (output row id)
    int j   = rp & 63;
    int img = rp >> 6;  // b*3 + c, in [0, 48)

    const float* row0 = x + (((size_t)img * 128 + 2 * j) * 128) + 4 * kp;
    const float* row1 = row0 + 128;
    float4 r0 = *(const float4*)row0;  // im[2j, 4kp .. 4kp+3]
    float4 r1 = *(const float4*)row1;  // im[2j+1, ...]

    float2 res;
    res.x = ev4(r0.x, r0.y, r1.x, r1.y);
    res.y = ev4(r0.z, r0.w, r1.z, r1.w);

    *(float2*)(out + (size_t)rp * 64 + 2 * kp) = res;
}

extern "C" void kernel_launch(void* const* d_in, const int* in_sizes, int n_in,
                              void* d_out, int out_size, void* d_ws, size_t ws_size,
                              hipStream_t stream) {
    const float* x = (const float*)d_in[0];   // [16,3,128,128]
    // d_in[1] = U3_w [8,3] — provably does not affect expval(Z on wire 4).
    float* out = (float*)d_out;               // [16,3,64,64] = 196608

    const int n_pairs = 16 * 3 * 64 * 32;     // 98304 threads, 2 outputs each
    const int block = 256;
    const int grid = (n_pairs + block - 1) / block;  // 384
    fqcnn_kernel<<<grid, block, 0, stream>>>(x, out, n_pairs);
}